// Round 1
// baseline (211.153 us; speedup 1.0000x reference)
//
#include <hip/hip_runtime.h>
#include <math.h>

// Problem constants (B,S,D,P,M from the reference)
#define BB 4
#define SS 8192
#define DD 512
#define PP 32
#define TT (PP + SS)           // 8224 tokens after concat
#define EPSV 1e-5f

// ---------------------------------------------------------------------------
// Stage 1: csum[b,d] = sum over s of x[b,s,d]  (chunked, atomic combine)
// Grid: BB*64 blocks (64 chunks of 128 rows per batch), 512 threads.
// Each thread accumulates one float4 column-group over its chunk.
// ---------------------------------------------------------------------------
__global__ __launch_bounds__(512) void k_colsum(const float4* __restrict__ x4,
                                                float* __restrict__ csum) {
  const int bb    = blockIdx.x >> 6;    // batch
  const int chunk = blockIdx.x & 63;    // 128-row chunk
  const int tid   = threadIdx.x;

  // float4 base of this chunk: rows [chunk*128, chunk*128+128) of batch bb
  const float4* p = x4 + ((size_t)bb * SS + (size_t)chunk * 128) * (DD / 4);

  float ax = 0.f, ay = 0.f, az = 0.f, aw = 0.f;
#pragma unroll 4
  for (int i = 0; i < 32; ++i) {        // 32*512 = 16384 float4 = 128 rows
    float4 t = p[(size_t)i * 512 + tid];
    ax += t.x; ay += t.y; az += t.z; aw += t.w;
  }

  __shared__ float4 sh[512];
  sh[tid] = make_float4(ax, ay, az, aw);
  __syncthreads();

  // threads tid, tid+128, tid+256, tid+384 hold the same column group tid%128
  if (tid < 128) {
    float4 a0 = sh[tid], a1 = sh[tid + 128], a2 = sh[tid + 256], a3 = sh[tid + 384];
    float* dst = csum + bb * DD + tid * 4;
    atomicAdd(dst + 0, a0.x + a1.x + a2.x + a3.x);
    atomicAdd(dst + 1, a0.y + a1.y + a2.y + a3.y);
    atomicAdd(dst + 2, a0.z + a1.z + a2.z + a3.z);
    atomicAdd(dst + 3, a0.w + a1.w + a2.w + a3.w);
  }
}

// ---------------------------------------------------------------------------
// Stage 2: per batch (one block of 512 threads):
//   cbar = (csum + sum_p pm) / T
//   vbar = cbar @ Wv + bv
//   y    = LN(vbar)*gamma + beta
//   z    = y @ Wout + bout
// ---------------------------------------------------------------------------
__global__ __launch_bounds__(512) void k_project(const float* __restrict__ csum,
                                                 const float* __restrict__ pm,
                                                 const float* __restrict__ Wv,
                                                 const float* __restrict__ bv,
                                                 const float* __restrict__ gamma,
                                                 const float* __restrict__ beta,
                                                 const float* __restrict__ Wout,
                                                 const float* __restrict__ bout,
                                                 float* __restrict__ z) {
  const int bb = blockIdx.x;
  const int j  = threadIdx.x;

  __shared__ float a[DD];
  __shared__ float y[DD];
  __shared__ float wsum1[8], wsum2[8];

  // cbar[j] = (x colsum + persistent-memory colsum) / T
  float s = csum[bb * DD + j];
#pragma unroll
  for (int p = 0; p < PP; ++p) s += pm[p * DD + j];
  a[j] = s * (1.0f / (float)TT);
  __syncthreads();

  // vbar[j] = dot(cbar, Wv[:,j]) + bv[j]
  float acc = bv[j];
#pragma unroll 8
  for (int d = 0; d < DD; ++d) acc += a[d] * Wv[d * DD + j];

  // block mean/var of acc across 512 threads (wave64 shuffle + LDS)
  float v1 = acc, v2 = acc * acc;
#pragma unroll
  for (int off = 32; off > 0; off >>= 1) {
    v1 += __shfl_down(v1, off, 64);
    v2 += __shfl_down(v2, off, 64);
  }
  const int wave = j >> 6;
  if ((j & 63) == 0) { wsum1[wave] = v1; wsum2[wave] = v2; }
  __syncthreads();
  float t1 = 0.f, t2 = 0.f;
#pragma unroll
  for (int w = 0; w < 8; ++w) { t1 += wsum1[w]; t2 += wsum2[w]; }
  const float mu  = t1 * (1.0f / (float)DD);
  const float var = t2 * (1.0f / (float)DD) - mu * mu;
  const float inv = 1.0f / sqrtf(var + EPSV);

  y[j] = (acc - mu) * inv * gamma[j] + beta[j];
  __syncthreads();

  // z[j] = dot(y, Wout[:,j]) + bout[j]
  float acc2 = bout[j];
#pragma unroll 8
  for (int d = 0; d < DD; ++d) acc2 += y[d] * Wout[d * DD + j];
  z[bb * DD + j] = acc2;
}

// ---------------------------------------------------------------------------
// Stage 3: broadcast z[b,:] to out[b,t,:] for all t in [0,T). float4 stores.
// Total float4 elements = B*T*D/4 = 4,210,688 → 16448 blocks of 256.
// ---------------------------------------------------------------------------
__global__ __launch_bounds__(256) void k_bcast(const float4* __restrict__ z4,
                                               float4* __restrict__ out4) {
  const unsigned i  = blockIdx.x * 256u + threadIdx.x;     // float4 index
  const unsigned bb = i / 1052672u;                        // T*D/4 per batch
  const unsigned j4 = i & 127u;                            // column group (D/4=128)
  out4[i] = z4[bb * 128u + j4];
}

// ---------------------------------------------------------------------------
extern "C" void kernel_launch(void* const* d_in, const int* in_sizes, int n_in,
                              void* d_out, int out_size, void* d_ws, size_t ws_size,
                              hipStream_t stream) {
  // setup_inputs() order:
  // 0:x  1:persistent_memory  2:Wk 3:bk  4:Wv 5:bv  6:Wq 7:bq
  // 8:gamma 9:beta  10:Wout 11:bout      (Wk/bk/Wq/bq are mathematically dead)
  const float* x     = (const float*)d_in[0];
  const float* pm    = (const float*)d_in[1];
  const float* Wv    = (const float*)d_in[4];
  const float* bv    = (const float*)d_in[5];
  const float* gamma = (const float*)d_in[8];
  const float* beta  = (const float*)d_in[9];
  const float* Wout  = (const float*)d_in[10];
  const float* bout  = (const float*)d_in[11];

  float* csum = (float*)d_ws;        // BB*DD floats (8 KB)
  float* z    = csum + BB * DD;      // BB*DD floats (8 KB)

  // ws is poisoned before every launch — zero the accumulator region.
  hipMemsetAsync(csum, 0, BB * DD * sizeof(float), stream);

  k_colsum<<<BB * 64, 512, 0, stream>>>((const float4*)x, csum);

  k_project<<<BB, 512, 0, stream>>>(csum, pm, Wv, bv, gamma, beta, Wout, bout, z);

  const unsigned total4 = (unsigned)BB * TT * DD / 4;      // 4,210,688
  k_bcast<<<total4 / 256, 256, 0, stream>>>((const float4*)z, (float4*)d_out);
}

// Round 2
// 153.908 us; speedup vs baseline: 1.3719x; 1.3719x over previous
//
#include <hip/hip_runtime.h>
#include <math.h>

// Problem constants (B,S,D,P,M from the reference)
#define BB 4
#define SS 8192
#define DD 512
#define PP 32
#define TT (PP + SS)           // 8224 tokens after concat
#define EPSV 1e-5f

// ws layout (floats): csum[BB*DD] | vbar[BB*DD] | z[BB*DD]   (24 KB total)

// ---------------------------------------------------------------------------
// Stage 1: csum[b,d] = sum_s x[b,s,d].  Grid: BB*128 blocks (64-row chunks),
// 512 threads. Fully unrolled: 16 float4 loads in flight per thread.
// ---------------------------------------------------------------------------
__global__ __launch_bounds__(512) void k_colsum(const float4* __restrict__ x4,
                                                float* __restrict__ csum) {
  const int bb    = blockIdx.x >> 7;    // batch
  const int chunk = blockIdx.x & 127;   // 64-row chunk
  const int tid   = threadIdx.x;

  const float4* p = x4 + ((size_t)bb * SS + (size_t)chunk * 64) * (DD / 4);

  float ax = 0.f, ay = 0.f, az = 0.f, aw = 0.f;
#pragma unroll
  for (int i = 0; i < 16; ++i) {        // 16*512 = 8192 float4 = 64 rows
    float4 t = p[i * 512 + tid];
    ax += t.x; ay += t.y; az += t.z; aw += t.w;
  }

  __shared__ float4 sh[512];
  sh[tid] = make_float4(ax, ay, az, aw);
  __syncthreads();

  // threads tid, tid+128, tid+256, tid+384 share column group tid&127
  if (tid < 128) {
    float4 a0 = sh[tid], a1 = sh[tid + 128], a2 = sh[tid + 256], a3 = sh[tid + 384];
    float* dst = csum + bb * DD + tid * 4;
    atomicAdd(dst + 0, a0.x + a1.x + a2.x + a3.x);
    atomicAdd(dst + 1, a0.y + a1.y + a2.y + a3.y);
    atomicAdd(dst + 2, a0.z + a1.z + a2.z + a3.z);
    atomicAdd(dst + 3, a0.w + a1.w + a2.w + a3.w);
  }
}

// ---------------------------------------------------------------------------
// Stage 2: vbar[b,j] += sum_{d in chunk} cbar[b,d] * Wv[d,j]
// Grid: BB*32 blocks (16-row chunks of Wv), 512 threads (one column each).
// cbar[d] = (csum[b,d] + sum_p pm[p,d]) / T computed on the fly (cheap).
// ---------------------------------------------------------------------------
__global__ __launch_bounds__(512) void k_vbar(const float* __restrict__ csum,
                                              const float* __restrict__ pm,
                                              const float* __restrict__ Wv,
                                              float* __restrict__ vbar) {
  const int bb = blockIdx.x >> 5;       // batch
  const int ch = blockIdx.x & 31;       // 16-row chunk
  const int j  = threadIdx.x;

  __shared__ float a[16];
  if (j < 16) {
    const int d = ch * 16 + j;
    float s = csum[bb * DD + d];
#pragma unroll
    for (int p = 0; p < PP; ++p) s += pm[p * DD + d];
    a[j] = s * (1.0f / (float)TT);
  }
  __syncthreads();

  float acc = 0.f;
#pragma unroll
  for (int i = 0; i < 16; ++i)
    acc += a[i] * Wv[(ch * 16 + i) * DD + j];

  atomicAdd(&vbar[bb * DD + j], acc);
}

// ---------------------------------------------------------------------------
// Stage 3: z[b,j] += sum_{d in chunk} y[b,d] * Wout[d,j], where
// y = LN(vbar+bv)*gamma+beta is recomputed redundantly per block (trivial).
// Grid: BB*32 blocks, 512 threads.
// ---------------------------------------------------------------------------
__global__ __launch_bounds__(512) void k_zmat(const float* __restrict__ vbar,
                                              const float* __restrict__ bv,
                                              const float* __restrict__ gamma,
                                              const float* __restrict__ beta,
                                              const float* __restrict__ Wout,
                                              float* __restrict__ z) {
  const int bb = blockIdx.x >> 5;
  const int ch = blockIdx.x & 31;
  const int j  = threadIdx.x;

  const float v = vbar[bb * DD + j] + bv[j];

  // block mean/var across 512 threads
  float v1 = v, v2 = v * v;
#pragma unroll
  for (int off = 32; off > 0; off >>= 1) {
    v1 += __shfl_down(v1, off, 64);
    v2 += __shfl_down(v2, off, 64);
  }
  __shared__ float w1[8], w2[8];
  const int wave = j >> 6;
  if ((j & 63) == 0) { w1[wave] = v1; w2[wave] = v2; }
  __syncthreads();
  float t1 = 0.f, t2 = 0.f;
#pragma unroll
  for (int w = 0; w < 8; ++w) { t1 += w1[w]; t2 += w2[w]; }
  const float mu  = t1 * (1.0f / (float)DD);
  const float var = t2 * (1.0f / (float)DD) - mu * mu;
  const float inv = 1.0f / sqrtf(var + EPSV);

  __shared__ float y[DD];
  y[j] = (v - mu) * inv * gamma[j] + beta[j];
  __syncthreads();

  float acc = 0.f;
#pragma unroll
  for (int i = 0; i < 16; ++i)
    acc += y[ch * 16 + i] * Wout[(ch * 16 + i) * DD + j];

  atomicAdd(&z[bb * DD + j], acc);
}

// ---------------------------------------------------------------------------
// Stage 4: out[b,t,:] = z[b,:] + bout  broadcast over all t. float4 stores.
// ---------------------------------------------------------------------------
__global__ __launch_bounds__(256) void k_bcast(const float4* __restrict__ z4,
                                               const float4* __restrict__ bout4,
                                               float4* __restrict__ out4) {
  const unsigned i  = blockIdx.x * 256u + threadIdx.x;     // float4 index
  const unsigned bb = i / 1052672u;                        // T*D/4 per batch
  const unsigned j4 = i & 127u;                            // column group (D/4=128)
  float4 zz = z4[bb * 128u + j4];
  float4 bo = bout4[j4];
  out4[i] = make_float4(zz.x + bo.x, zz.y + bo.y, zz.z + bo.z, zz.w + bo.w);
}

// ---------------------------------------------------------------------------
extern "C" void kernel_launch(void* const* d_in, const int* in_sizes, int n_in,
                              void* d_out, int out_size, void* d_ws, size_t ws_size,
                              hipStream_t stream) {
  // setup_inputs() order:
  // 0:x 1:persistent_memory 2:Wk 3:bk 4:Wv 5:bv 6:Wq 7:bq 8:gamma 9:beta
  // 10:Wout 11:bout      (Wk/bk/Wq/bq are mathematically dead — see round 1)
  const float* x     = (const float*)d_in[0];
  const float* pm    = (const float*)d_in[1];
  const float* Wv    = (const float*)d_in[4];
  const float* bv    = (const float*)d_in[5];
  const float* gamma = (const float*)d_in[8];
  const float* beta  = (const float*)d_in[9];
  const float* Wout  = (const float*)d_in[10];
  const float* bout  = (const float*)d_in[11];

  float* csum = (float*)d_ws;        // BB*DD floats
  float* vbar = csum + BB * DD;      // BB*DD floats
  float* z    = vbar + BB * DD;      // BB*DD floats

  // zero all three accumulator regions (ws is re-poisoned before every call)
  hipMemsetAsync(csum, 0, 3 * BB * DD * sizeof(float), stream);

  k_colsum<<<BB * 128, 512, 0, stream>>>((const float4*)x, csum);

  k_vbar<<<BB * 32, 512, 0, stream>>>(csum, pm, Wv, vbar);

  k_zmat<<<BB * 32, 512, 0, stream>>>(vbar, bv, gamma, beta, Wout, z);

  const unsigned total4 = (unsigned)BB * TT * DD / 4;      // 4,210,688
  k_bcast<<<total4 / 256, 256, 0, stream>>>((const float4*)z,
                                            (const float4*)bout,
                                            (float4*)d_out);
}